// Round 2
// baseline (509.222 us; speedup 1.0000x reference)
//
#include <hip/hip_runtime.h>
#include <hip/hip_bf16.h>

typedef unsigned char u8;
typedef unsigned short u16;
typedef unsigned int u32;

#define PP     254016   // 504*504
#define PADW   514
#define PADP   264196   // 514*514
#define NPIX   2032128  // 8*PP
#define NTRIP  4913     // 17^3
#define N_F    2032128.0
#define RROWS  14       // 504 = 14*36

__device__ __forceinline__ float bf2f(__hip_bfloat16 h){ return __bfloat162float(h); }
__device__ __forceinline__ u16 f2bf(float f){
  u32 u = __float_as_uint(f);
  return (u16)((u + 0x7FFFu + ((u >> 16) & 1u)) >> 16);   // RNE
}
// dual-dtype load: flag==1 -> float32, flag==0 -> bf16
__device__ __forceinline__ float ldv(const void* p, int i, u32 f){
  return f ? ((const float*)p)[i] : bf2f(((const __hip_bfloat16*)p)[i]);
}

// ---------------- K0: dtype detect (1 wave) ----------------
// bf16 uniform[0,1] words never have the sign bit set; f32 low-halves are
// random mantissa bits -> ~half have it. Scan 1024 words.
__global__ __launch_bounds__(64) void k_detect(const u16* __restrict__ xw, u32* __restrict__ flag){
  int t = threadIdx.x;
  u32 bad = 0;
  for (int i = t; i < 1024; i += 64) bad |= (u32)(xw[i] >> 15);
  int anybad = __any((int)bad);
  if (t == 0) *flag = anybad ? 1u : 0u;
}

// ---------------- K1: bins (zero-padded 514x514 per plane) ----------------
__global__ __launch_bounds__(256) void k_bins(const void* __restrict__ x, u8* __restrict__ bins,
                                              const u32* __restrict__ flag){
  u32 f = *flag;
  int plane = blockIdx.y;
  int pix = blockIdx.x*256 + threadIdx.x;
  if (pix >= PADP) return;
  int r = pix / PADW; int c = pix - r*PADW;
  u8 v = 0;
  if (r >= 1 && r <= 512 && c >= 1 && c <= 512){
    float xv = ldv(x, plane*262144 + (r-1)*512 + (c-1), f);
    v = (u8)(int)rintf((xv * 255.0f) * 0.0625f);   // round(x*255/16); exact: x*255 fits f32, /16 exact
  }
  bins[(size_t)plane*PADP + pix] = v;
}

// ---------------- K2: 11x11 sliding-window mode ----------------
// One block per (plane, row-block of RROWS). Thread t owns column t (and 512+t for t<2):
// maintains vertical 11-row counts nibble-packed in 3 words, shares via LDS; output
// threads widen to bytes, sum 11 columns, argmax with first-max tie-break.
__global__ __launch_bounds__(512) void k_mode(const u8* __restrict__ bins, u8* __restrict__ modes){
  int plane = blockIdx.y;
  int r0 = blockIdx.x * RROWS;
  const u8* bp = bins + (size_t)plane*PADP;
  u8* mp = modes + (size_t)plane*PP;
  __shared__ u32 vcbuf[PADW*3];
  int t = threadIdx.x;
  bool extra = (t < 2);
  int colB = 512 + t;
  u32 v0=0,v1=0,v2w=0, w0=0,w1=0,w2w=0;
  for (int j=0;j<10;j++){
    int row = r0 + j;
    { int b = bp[row*PADW + t]; u32 d = 1u << ((b & 7) * 4);
      v0 += (b < 8) ? d : 0u; v1 += (b >= 8 && b < 16) ? d : 0u; v2w += (b == 16) ? 1u : 0u; }
    if (extra){ int b = bp[row*PADW + colB]; u32 d = 1u << ((b & 7) * 4);
      w0 += (b < 8) ? d : 0u; w1 += (b >= 8 && b < 16) ? d : 0u; w2w += (b == 16) ? 1u : 0u; }
  }
  for (int i=0;i<RROWS;i++){
    int r = r0 + i;
    { int b = bp[(r+10)*PADW + t]; u32 d = 1u << ((b & 7) * 4);
      v0 += (b < 8) ? d : 0u; v1 += (b >= 8 && b < 16) ? d : 0u; v2w += (b == 16) ? 1u : 0u; }
    if (extra){ int b = bp[(r+10)*PADW + colB]; u32 d = 1u << ((b & 7) * 4);
      w0 += (b < 8) ? d : 0u; w1 += (b >= 8 && b < 16) ? d : 0u; w2w += (b == 16) ? 1u : 0u; }
    vcbuf[t*3+0]=v0; vcbuf[t*3+1]=v1; vcbuf[t*3+2]=v2w;
    if (extra){ vcbuf[colB*3+0]=w0; vcbuf[colB*3+1]=w1; vcbuf[colB*3+2]=w2w; }
    __syncthreads();
    if (t < 504){
      u32 h0=0,h1=0,h2=0,h3=0,h4=0;
      #pragma unroll
      for (int dx=0; dx<11; dx++){
        int base = (t+dx)*3;
        u32 n0 = vcbuf[base], n1 = vcbuf[base+1], n2 = vcbuf[base+2];
        h0 += n0 & 0x0F0F0F0Fu;          // bins {0,2,4,6}
        h1 += (n0 >> 4) & 0x0F0F0F0Fu;   // bins {1,3,5,7}
        h2 += n1 & 0x0F0F0F0Fu;          // bins {8,10,12,14}
        h3 += (n1 >> 4) & 0x0F0F0F0Fu;   // bins {9,11,13,15}
        h4 += n2;                        // bin 16 (plain word)
      }
      u32 best = h4 << 5;                // key for bin16: (cnt<<5)|0
      #pragma unroll
      for (int b=0;b<16;b++){
        u32 word = (b & 1) ? ((b < 8) ? h1 : h3) : ((b < 8) ? h0 : h2);
        u32 cnt = (word >> (((b >> 1) & 3) * 8)) & 0xFFu;
        u32 key = (cnt << 5) | (u32)(16 - b);     // ties -> smallest bin (first max)
        best = (key > best) ? key : best;
      }
      mp[r*504 + t] = (u8)(16u - (best & 31u));
    }
    __syncthreads();
    { int b = bp[r*PADW + t]; u32 d = 1u << ((b & 7) * 4);
      v0 -= (b < 8) ? d : 0u; v1 -= (b >= 8 && b < 16) ? d : 0u; v2w -= (b == 16) ? 1u : 0u; }
    if (extra){ int b = bp[r*PADW + colB]; u32 d = 1u << ((b & 7) * 4);
      w0 -= (b < 8) ? d : 0u; w1 -= (b >= 8 && b < 16) ? d : 0u; w2w -= (b == 16) ? 1u : 0u; }
  }
}

// ---------------- K3: triple index + histogram ----------------
__global__ __launch_bounds__(256) void k_triple(const u8* __restrict__ modes, u16* __restrict__ triple, u32* __restrict__ hist){
  __shared__ u32 lh[NTRIP];
  for (int i=threadIdx.x;i<NTRIP;i+=256) lh[i]=0;
  __syncthreads();
  int stride = gridDim.x*256;
  for (int p = blockIdx.x*256 + threadIdx.x; p < NPIX; p += stride){
    int bimg = p / PP; int pix = p - bimg*PP;
    const u8* mb = modes + (size_t)bimg*3*PP + pix;
    int m0 = mb[0], m1 = mb[PP], m2 = mb[2*PP];
    int idx = (m0*17 + m1)*17 + m2;
    triple[p] = (u16)idx;
    atomicAdd(&lh[idx], 1u);
  }
  __syncthreads();
  for (int i=threadIdx.x;i<NTRIP;i+=256){ u32 v = lh[i]; if (v) atomicAdd(&hist[i], v); }
}

// ---------------- K4a: stage-1 BN stats -> folded params P1[4][32] ----------------
__global__ __launch_bounds__(256) void k_stats1(const u32* __restrict__ hist,
    const void* w1, const void* b1, const void* wd1, const void* bd1,
    const void* g1, const void* be1, float* __restrict__ P1, const u32* __restrict__ flag){
  u32 f = *flag;
  int o = threadIdx.x & 31;
  int slice = threadIdx.x >> 5;
  float wd = ldv(wd1, o, f);
  float q0 = wd * ldv(w1, o*3+0, f);
  float q1 = wd * ldv(w1, o*3+1, f);
  float q2 = wd * ldv(w1, o*3+2, f);
  float qc = wd * ldv(b1, o, f) + ldv(bd1, o, f);
  double s=0.0, q=0.0;
  for (int t=slice; t<NTRIP; t+=8){
    int m2 = t % 17; int tt = t / 17; int m1 = tt % 17; int m0 = tt / 17;
    float v = q0*(m0*(1.f/16.f)) + q1*(m1*(1.f/16.f)) + q2*(m2*(1.f/16.f)) + qc;
    double c = (double)hist[t];
    s += c * (double)v;
    q += c * (double)v * (double)v;
  }
  __shared__ double rs[256], rq[256];
  rs[threadIdx.x]=s; rq[threadIdx.x]=q;
  __syncthreads();
  if (slice == 0){
    for (int j=1;j<8;j++){ s += rs[o + j*32]; q += rq[o + j*32]; }
    double mean = s / N_F;
    double var  = q / N_F - mean*mean;
    double rstd = 1.0 / sqrt(var + 1e-5);
    double A = rstd * (double)ldv(g1, o, f);
    double B = (double)ldv(be1, o, f) - mean * A;
    P1[o]      = (float)((double)q0 * A);
    P1[32+o]   = (float)((double)q1 * A);
    P1[64+o]   = (float)((double)q2 * A);
    P1[96+o]   = (float)((double)qc * A + B);
  }
}

// ---------------- K4b: stage-2 BN stats (one block per output channel) ----------------
__global__ __launch_bounds__(256) void k_stats2(const u32* __restrict__ hist, const float* __restrict__ P1,
    const void* w2, const void* b2, const void* wd2, const void* bd2,
    double* __restrict__ sums2, const u32* __restrict__ flag){
  u32 f = *flag;
  int o = blockIdx.x;
  __shared__ float sP[128];
  __shared__ float sw[32];
  for (int i=threadIdx.x;i<128;i+=256) sP[i] = P1[i];
  for (int i=threadIdx.x;i<32;i+=256) sw[i] = ldv(w2, o*32+i, f);
  __syncthreads();
  float wd = ldv(wd2, o, f);
  float cc = wd * ldv(b2, o, f) + ldv(bd2, o, f);
  double s=0.0, q=0.0;
  for (int t=threadIdx.x; t<NTRIP; t+=256){
    int m2 = t % 17; int tt = t / 17; int m1 = tt % 17; int m0 = tt / 17;
    float f0 = m0*(1.f/16.f), f1 = m1*(1.f/16.f), f2 = m2*(1.f/16.f);
    float dot = 0.f;
    #pragma unroll
    for (int c=0;c<32;c++){
      float u = sP[c]*f0 + sP[32+c]*f1 + sP[64+c]*f2 + sP[96+c];
      float y = (u >= 0.f) ? u : 0.01f*u;
      dot += sw[c]*y;
    }
    float v2 = wd*dot + cc;
    double cn = (double)hist[t];
    s += cn*(double)v2;
    q += cn*(double)v2*(double)v2;
  }
  __shared__ double red[256];
  red[threadIdx.x]=s; __syncthreads();
  for (int off=128; off>0; off>>=1){ if (threadIdx.x<off) red[threadIdx.x]+=red[threadIdx.x+off]; __syncthreads(); }
  if (threadIdx.x==0) sums2[o]=red[0];
  __syncthreads();
  red[threadIdx.x]=q; __syncthreads();
  for (int off=128; off>0; off>>=1){ if (threadIdx.x<off) red[threadIdx.x]+=red[threadIdx.x+off]; __syncthreads(); }
  if (threadIdx.x==0) sums2[32+o]=red[0];
}

// ---------------- K4c: build LUT[4913][32] ----------------
__global__ __launch_bounds__(256) void k_lut(const double* __restrict__ sums2, const float* __restrict__ P1,
    const void* w2, const void* b2, const void* wd2, const void* bd2,
    const void* g2, const void* be2, float* __restrict__ lut, const u32* __restrict__ flag){
  u32 f = *flag;
  __shared__ float sP[128];
  __shared__ float sw[1024];
  __shared__ float ka[32], kb[32];
  for (int i=threadIdx.x;i<128;i+=256) sP[i]=P1[i];
  for (int i=threadIdx.x;i<1024;i+=256) sw[i]=ldv(w2, i, f);
  if (threadIdx.x < 32){
    int o = threadIdx.x;
    double mean = sums2[o] / N_F;
    double var  = sums2[32+o] / N_F - mean*mean;
    double rstd = 1.0 / sqrt(var + 1e-5);
    double A = rstd * (double)ldv(g2, o, f);
    double B = (double)ldv(be2, o, f) - mean*A;
    double wd = (double)ldv(wd2, o, f);
    ka[o] = (float)(wd*A);
    kb[o] = (float)((wd*(double)ldv(b2, o, f) + (double)ldv(bd2, o, f))*A + B);
  }
  __syncthreads();
  int t = blockIdx.x*256 + threadIdx.x;
  if (t >= NTRIP) return;
  int m2 = t % 17; int tt = t/17; int m1 = tt % 17; int m0 = tt/17;
  float f0=m0*(1.f/16.f), f1=m1*(1.f/16.f), f2=m2*(1.f/16.f);
  float y1[32];
  #pragma unroll
  for (int c=0;c<32;c++){
    float u = sP[c]*f0 + sP[32+c]*f1 + sP[64+c]*f2 + sP[96+c];
    y1[c] = (u>=0.f)?u:0.01f*u;
  }
  #pragma unroll
  for (int o=0;o<32;o++){
    float dot=0.f;
    #pragma unroll
    for (int c=0;c<32;c++) dot += sw[o*32+c]*y1[c];
    float v = dot*ka[o] + kb[o];
    lut[t*32+o] = (v>=0.f)?v:0.01f*v;
  }
}

// ---------------- K5: gather LUT -> output, pixel-pair packed stores ----------------
__global__ __launch_bounds__(256) void k_out(const u16* __restrict__ triple, const float* __restrict__ lut,
                                             void* __restrict__ out, const u32* __restrict__ flag){
  u32 f = *flag;
  int g = blockIdx.x*256 + threadIdx.x;
  if (g >= NPIX/2) return;
  int p0 = g*2;
  int bimg = p0 / PP; int pix = p0 - bimg*PP;
  u32 tt = *(const u32*)(triple + p0);
  const float4* La = (const float4*)(lut + (size_t)(tt & 0xFFFFu)*32);
  const float4* Lb = (const float4*)(lut + (size_t)(tt >> 16)*32);
  if (f){  // float32 output: per channel, 2 consecutive pixels = float2 store
    float* ob = (float*)out + (size_t)bimg*32*PP + pix;
    #pragma unroll
    for (int j=0;j<8;j++){
      float4 a = La[j]; float4 b = Lb[j];
      float2 v;
      v.x=a.x; v.y=b.x; *(float2*)(ob + (size_t)(4*j+0)*PP) = v;
      v.x=a.y; v.y=b.y; *(float2*)(ob + (size_t)(4*j+1)*PP) = v;
      v.x=a.z; v.y=b.z; *(float2*)(ob + (size_t)(4*j+2)*PP) = v;
      v.x=a.w; v.y=b.w; *(float2*)(ob + (size_t)(4*j+3)*PP) = v;
    }
  } else { // bf16 output: pack 2 pixels per dword
    u16* ob = (u16*)out + (size_t)bimg*32*PP + pix;
    #pragma unroll
    for (int j=0;j<8;j++){
      float4 a = La[j]; float4 b = Lb[j];
      *(u32*)(ob + (size_t)(4*j+0)*PP) = (u32)f2bf(a.x) | ((u32)f2bf(b.x)<<16);
      *(u32*)(ob + (size_t)(4*j+1)*PP) = (u32)f2bf(a.y) | ((u32)f2bf(b.y)<<16);
      *(u32*)(ob + (size_t)(4*j+2)*PP) = (u32)f2bf(a.z) | ((u32)f2bf(b.z)<<16);
      *(u32*)(ob + (size_t)(4*j+3)*PP) = (u32)f2bf(a.w) | ((u32)f2bf(b.w)<<16);
    }
  }
}

extern "C" void kernel_launch(void* const* d_in, const int* in_sizes, int n_in,
                              void* d_out, int out_size, void* d_ws, size_t ws_size,
                              hipStream_t stream){
  const void* x   = d_in[0];
  const void* w1  = d_in[1];
  const void* b1  = d_in[2];
  const void* wd1 = d_in[3];
  const void* bd1 = d_in[4];
  const void* g1  = d_in[5];
  const void* be1 = d_in[6];
  const void* w2  = d_in[7];
  const void* b2  = d_in[8];
  const void* wd2 = d_in[9];
  const void* bd2 = d_in[10];
  const void* g2  = d_in[11];
  const void* be2 = d_in[12];

  char* w = (char*)d_ws;
  auto alloc = [&](size_t bytes)->char* { char* p = w; w += (bytes + 255) & ~(size_t)255; return p; };
  u32*   flag   = (u32*)  alloc(256);
  u8*    bins   = (u8*)   alloc(24ull*PADP);       // 6.34 MB
  u8*    modes  = (u8*)   alloc(24ull*PP);         // 6.10 MB
  u16*   triple = (u16*)  alloc(2ull*NPIX);        // 4.06 MB
  u32*   hist   = (u32*)  alloc(4ull*NTRIP);
  float* P1     = (float*)alloc(128ull*4);
  double* sums2 = (double*)alloc(64ull*8);
  float* lut    = (float*)alloc(4ull*NTRIP*32);    // 629 KB

  k_detect<<<dim3(1), 64, 0, stream>>>((const u16*)x, flag);
  k_bins<<<dim3((PADP+255)/256, 24), 256, 0, stream>>>(x, bins, flag);
  k_mode<<<dim3(36, 24), 512, 0, stream>>>(bins, modes);
  hipMemsetAsync(hist, 0, 4ull*NTRIP, stream);
  k_triple<<<dim3(1984), 256, 0, stream>>>(modes, triple, hist);
  k_stats1<<<dim3(1), 256, 0, stream>>>(hist, w1, b1, wd1, bd1, g1, be1, P1, flag);
  k_stats2<<<dim3(32), 256, 0, stream>>>(hist, P1, w2, b2, wd2, bd2, sums2, flag);
  k_lut<<<dim3((NTRIP+255)/256), 256, 0, stream>>>(sums2, P1, w2, b2, wd2, bd2, g2, be2, lut, flag);
  k_out<<<dim3((NPIX/2)/256), 256, 0, stream>>>(triple, lut, d_out, flag);
}

// Round 3
// 442.587 us; speedup vs baseline: 1.1506x; 1.1506x over previous
//
#include <hip/hip_runtime.h>
#include <hip/hip_bf16.h>

typedef unsigned char u8;
typedef unsigned short u16;
typedef unsigned int u32;

#define PP     254016   // 504*504
#define PADW   514
#define PADP   264196   // 514*514
#define NPIX   2032128  // 8*PP
#define NTRIP  4913     // 17^3
#define N_F    2032128.0
#define RROWS  14       // 504 = 14*36

__device__ __forceinline__ float bf2f(__hip_bfloat16 h){ return __bfloat162float(h); }
__device__ __forceinline__ u32 f2bf(float f){
  u32 u = __float_as_uint(f);
  return ((u + 0x7FFFu + ((u >> 16) & 1u)) >> 16);   // RNE
}
// dual-dtype load: flag==1 -> float32, flag==0 -> bf16
__device__ __forceinline__ float ldv(const void* p, int i, u32 f){
  return f ? ((const float*)p)[i] : bf2f(((const __hip_bfloat16*)p)[i]);
}

// ---------------- K0: dtype detect + hist zero (1 block) ----------------
__global__ __launch_bounds__(256) void k_init(const u16* __restrict__ xw, u32* __restrict__ flag,
                                              u32* __restrict__ hist){
  int t = threadIdx.x;
  for (int i=t; i<NTRIP; i+=256) hist[i] = 0u;
  if (t < 64){
    u32 bad = 0;
    for (int i=t; i<1024; i+=64) bad |= (u32)(xw[i] >> 15);
    int anybad = __any((int)bad);
    if (t == 0) *flag = anybad ? 1u : 0u;
  }
}

// ---------------- K1: bins (zero-padded 514x514 per plane) ----------------
__global__ __launch_bounds__(256) void k_bins(const void* __restrict__ x, u8* __restrict__ bins,
                                              const u32* __restrict__ flag){
  u32 f = *flag;
  int plane = blockIdx.y;
  int pix = blockIdx.x*256 + threadIdx.x;
  if (pix >= PADP) return;
  int r = pix / PADW; int c = pix - r*PADW;
  u8 v = 0;
  if (r >= 1 && r <= 512 && c >= 1 && c <= 512){
    float xv = ldv(x, plane*262144 + (r-1)*512 + (c-1), f);
    v = (u8)(int)rintf((xv * 255.0f) * 0.0625f);   // round(x*255/16); /16 exact in f32
  }
  bins[(size_t)plane*PADP + pix] = v;
}

// ---------------- K2: 11x11 sliding-window mode ----------------
// 2-word nibble-packed vertical counts (bins 0-15; bin16 derived as 121-sum).
// Double-buffered column counts -> one __syncthreads per output row.
__global__ __launch_bounds__(512) void k_mode(const u8* __restrict__ bins, u8* __restrict__ modes){
  int plane = blockIdx.y;
  int r0 = blockIdx.x * RROWS;
  const u8* bp = bins + (size_t)plane*PADP;
  u8* mp = modes + (size_t)plane*PP;
  __shared__ u32 A0[2][516], A1[2][516];
  int t = threadIdx.x;
  bool extra = (t < 2);
  u32 v0=0, v1=0, w0=0, w1=0;
  #pragma unroll 1
  for (int j=0; j<11; j++){
    int row = r0 + j;
    { int b = bp[row*PADW + t]; u32 d = 1u << ((b & 7)*4);
      v0 += (b < 8) ? d : 0u; v1 += (b >= 8 && b < 16) ? d : 0u; }
    if (extra){ int b = bp[row*PADW + 512 + t]; u32 d = 1u << ((b & 7)*4);
      w0 += (b < 8) ? d : 0u; w1 += (b >= 8 && b < 16) ? d : 0u; }
  }
  A0[0][t] = v0; A1[0][t] = v1;
  if (extra){ A0[0][512+t] = w0; A1[0][512+t] = w1; }
  __syncthreads();
  for (int i=0; i<RROWS; i++){
    int r = r0 + i;
    int cur = i & 1, nxt = cur ^ 1;
    if (t < 504){
      u32 h0=0,h1=0,h2=0,h3=0;
      #pragma unroll
      for (int dx=0; dx<11; dx++){
        u32 n0 = A0[cur][t+dx], n1 = A1[cur][t+dx];
        h0 += n0 & 0x0F0F0F0Fu;          // bins {0,2,4,6}
        h1 += (n0 >> 4) & 0x0F0F0F0Fu;   // bins {1,3,5,7}
        h2 += n1 & 0x0F0F0F0Fu;          // bins {8,10,12,14}
        h3 += (n1 >> 4) & 0x0F0F0F0Fu;   // bins {9,11,13,15}
      }
      u32 T = h0 + h1 + h2 + h3;         // byte-slot sums <= 121, no carry
      u32 s = (T & 0xFFu) + ((T>>8)&0xFFu) + ((T>>16)&0xFFu) + (T>>24);
      u32 best = (121u - s) << 5;        // bin16 key: (cnt<<5)|0
      #pragma unroll
      for (int b=0;b<16;b++){
        u32 word = (b & 1) ? ((b < 8) ? h1 : h3) : ((b < 8) ? h0 : h2);
        u32 cnt = (word >> (((b >> 1) & 3) * 8)) & 0xFFu;
        u32 key = (cnt << 5) | (u32)(16 - b);     // ties -> smallest bin
        best = (key > best) ? key : best;
      }
      mp[r*504 + t] = (u8)(16u - (best & 31u));
    }
    if (i+1 < RROWS){
      { int b = bp[r*PADW + t]; u32 d = 1u << ((b & 7)*4);
        v0 -= (b < 8) ? d : 0u; v1 -= (b >= 8 && b < 16) ? d : 0u; }
      { int b = bp[(r+11)*PADW + t]; u32 d = 1u << ((b & 7)*4);
        v0 += (b < 8) ? d : 0u; v1 += (b >= 8 && b < 16) ? d : 0u; }
      if (extra){
        { int b = bp[r*PADW + 512 + t]; u32 d = 1u << ((b & 7)*4);
          w0 -= (b < 8) ? d : 0u; w1 -= (b >= 8 && b < 16) ? d : 0u; }
        { int b = bp[(r+11)*PADW + 512 + t]; u32 d = 1u << ((b & 7)*4);
          w0 += (b < 8) ? d : 0u; w1 += (b >= 8 && b < 16) ? d : 0u; }
      }
      A0[nxt][t] = v0; A1[nxt][t] = v1;
      if (extra){ A0[nxt][512+t] = w0; A1[nxt][512+t] = w1; }
    }
    __syncthreads();
  }
}

// ---------------- K3: triple index + histogram ----------------
__global__ __launch_bounds__(256) void k_triple(const u8* __restrict__ modes, u16* __restrict__ triple, u32* __restrict__ hist){
  __shared__ u32 lh[NTRIP];
  for (int i=threadIdx.x;i<NTRIP;i+=256) lh[i]=0;
  __syncthreads();
  int stride = gridDim.x*256;
  for (int p = blockIdx.x*256 + threadIdx.x; p < NPIX; p += stride){
    int bimg = p / PP; int pix = p - bimg*PP;
    const u8* mb = modes + (size_t)bimg*3*PP + pix;
    int m0 = mb[0], m1 = mb[PP], m2 = mb[2*PP];
    int idx = (m0*17 + m1)*17 + m2;
    triple[p] = (u16)idx;
    atomicAdd(&lh[idx], 1u);
  }
  __syncthreads();
  for (int i=threadIdx.x;i<NTRIP;i+=256){ u32 v = lh[i]; if (v) atomicAdd(&hist[i], v); }
}

// ---- shared device helper: compute 9 integer moments + stage-1 folded P1 ----
// Must be called by all 256 threads of a block; fills sP[128]. Uses hist.
__device__ __forceinline__ void compute_P1(const u32* __restrict__ hist,
    const void* w1, const void* b1, const void* wd1, const void* bd1,
    const void* g1, const void* be1, u32 f, float* sP /*LDS[128]*/,
    u32* wred /*LDS[4*9]*/, u32* mom /*LDS[9]*/){
  u32 a0=0,a1=0,a2=0,a3=0,a4=0,a5=0,a6=0,a7=0,a8=0;
  for (int t=threadIdx.x; t<NTRIP; t+=256){
    u32 c = hist[t];
    int m2 = t % 17; int tt = t/17; int m1 = tt % 17; int m0 = tt/17;
    a0 += c*m0; a1 += c*m1; a2 += c*m2;
    a3 += c*m0*m0; a4 += c*m1*m1; a5 += c*m2*m2;
    a6 += c*m0*m1; a7 += c*m0*m2; a8 += c*m1*m2;
  }
  #pragma unroll
  for (int s=1; s<64; s<<=1){
    a0 += __shfl_xor(a0,s); a1 += __shfl_xor(a1,s); a2 += __shfl_xor(a2,s);
    a3 += __shfl_xor(a3,s); a4 += __shfl_xor(a4,s); a5 += __shfl_xor(a5,s);
    a6 += __shfl_xor(a6,s); a7 += __shfl_xor(a7,s); a8 += __shfl_xor(a8,s);
  }
  int wv = threadIdx.x >> 6;
  if ((threadIdx.x & 63) == 0){
    wred[wv*9+0]=a0; wred[wv*9+1]=a1; wred[wv*9+2]=a2; wred[wv*9+3]=a3; wred[wv*9+4]=a4;
    wred[wv*9+5]=a5; wred[wv*9+6]=a6; wred[wv*9+7]=a7; wred[wv*9+8]=a8;
  }
  __syncthreads();
  if (threadIdx.x < 9) mom[threadIdx.x] = wred[threadIdx.x] + wred[9+threadIdx.x] + wred[18+threadIdx.x] + wred[27+threadIdx.x];
  __syncthreads();
  if (threadIdx.x < 32){
    int o = threadIdx.x;
    double wd = ldv(wd1,o,f);
    double q0 = wd*ldv(w1,o*3+0,f), q1 = wd*ldv(w1,o*3+1,f), q2 = wd*ldv(w1,o*3+2,f);
    double qc = wd*ldv(b1,o,f) + ldv(bd1,o,f);
    double S0=mom[0],S1=mom[1],S2=mom[2],S00=mom[3],S11=mom[4],S22=mom[5],S01=mom[6],S02=mom[7],S12=mom[8];
    double lin = (q0*S0 + q1*S1 + q2*S2) * (1.0/16.0);
    double mean = lin/N_F + qc;
    double quad = (q0*q0*S00 + q1*q1*S11 + q2*q2*S22 + 2.0*(q0*q1*S01 + q0*q2*S02 + q1*q2*S12)) * (1.0/256.0);
    double Ev2 = quad/N_F + 2.0*qc*lin/N_F + qc*qc;
    double var = Ev2 - mean*mean;
    double rstd = 1.0 / sqrt(var + 1e-5);
    double A = rstd * ldv(g1,o,f);
    double B = ldv(be1,o,f) - mean*A;
    sP[o]      = (float)(q0*A);
    sP[32+o]   = (float)(q1*A);
    sP[64+o]   = (float)(q2*A);
    sP[96+o]   = (float)(qc*A + B);
  }
  __syncthreads();
}

// ---------------- K4: stage-2 BN sums (one block per output channel) ----------------
__global__ __launch_bounds__(256) void k_stats2(const u32* __restrict__ hist,
    const void* w1, const void* b1, const void* wd1, const void* bd1, const void* g1, const void* be1,
    const void* w2, const void* b2, const void* wd2, const void* bd2,
    double* __restrict__ sums2, const u32* __restrict__ flag){
  u32 f = *flag;
  int o = blockIdx.x;
  __shared__ float sP[128];
  __shared__ u32 wred[36], mom[9];
  __shared__ float sw[32];
  compute_P1(hist, w1,b1,wd1,bd1,g1,be1, f, sP, wred, mom);
  for (int i=threadIdx.x;i<32;i+=256) sw[i] = ldv(w2, o*32+i, f);
  __syncthreads();
  float wd = ldv(wd2, o, f);
  float cc = wd * ldv(b2, o, f) + ldv(bd2, o, f);
  double s=0.0, q=0.0;
  for (int t=threadIdx.x; t<NTRIP; t+=256){
    int m2 = t % 17; int tt = t / 17; int m1 = tt % 17; int m0 = tt / 17;
    float f0 = m0*(1.f/16.f), f1 = m1*(1.f/16.f), f2 = m2*(1.f/16.f);
    float dot = 0.f;
    #pragma unroll
    for (int c=0;c<32;c++){
      float u = sP[c]*f0 + sP[32+c]*f1 + sP[64+c]*f2 + sP[96+c];
      float y = (u >= 0.f) ? u : 0.01f*u;
      dot += sw[c]*y;
    }
    float v2 = wd*dot + cc;
    double cn = (double)hist[t];
    s += cn*(double)v2;
    q += cn*(double)v2*(double)v2;
  }
  __shared__ double red[256];
  red[threadIdx.x]=s; __syncthreads();
  for (int off=128; off>0; off>>=1){ if (threadIdx.x<off) red[threadIdx.x]+=red[threadIdx.x+off]; __syncthreads(); }
  if (threadIdx.x==0) sums2[o]=red[0];
  __syncthreads();
  red[threadIdx.x]=q; __syncthreads();
  for (int off=128; off>0; off>>=1){ if (threadIdx.x<off) red[threadIdx.x]+=red[threadIdx.x+off]; __syncthreads(); }
  if (threadIdx.x==0) sums2[32+o]=red[0];
}

// ---------------- K5: build LUTs (f32 and packed bf16) ----------------
__global__ __launch_bounds__(256) void k_lut(const u32* __restrict__ hist, const double* __restrict__ sums2,
    const void* w1, const void* b1, const void* wd1, const void* bd1, const void* g1, const void* be1,
    const void* w2, const void* b2, const void* wd2, const void* bd2,
    const void* g2, const void* be2,
    float* __restrict__ lutf, u32* __restrict__ lutb, const u32* __restrict__ flag){
  u32 f = *flag;
  __shared__ float sP[128];
  __shared__ u32 wred[36], mom[9];
  __shared__ float sw[1024];
  __shared__ float ka[32], kb[32];
  compute_P1(hist, w1,b1,wd1,bd1,g1,be1, f, sP, wred, mom);
  for (int i=threadIdx.x;i<1024;i+=256) sw[i]=ldv(w2, i, f);
  if (threadIdx.x < 32){
    int o = threadIdx.x;
    double mean = sums2[o] / N_F;
    double var  = sums2[32+o] / N_F - mean*mean;
    double rstd = 1.0 / sqrt(var + 1e-5);
    double A = rstd * (double)ldv(g2, o, f);
    double B = (double)ldv(be2, o, f) - mean*A;
    double wd = (double)ldv(wd2, o, f);
    ka[o] = (float)(wd*A);
    kb[o] = (float)((wd*(double)ldv(b2, o, f) + (double)ldv(bd2, o, f))*A + B);
  }
  __syncthreads();
  int t = blockIdx.x*256 + threadIdx.x;
  if (t >= NTRIP) return;
  int m2 = t % 17; int tt = t/17; int m1 = tt % 17; int m0 = tt/17;
  float f0=m0*(1.f/16.f), f1=m1*(1.f/16.f), f2=m2*(1.f/16.f);
  float y1[32];
  #pragma unroll
  for (int c=0;c<32;c++){
    float u = sP[c]*f0 + sP[32+c]*f1 + sP[64+c]*f2 + sP[96+c];
    y1[c] = (u>=0.f)?u:0.01f*u;
  }
  float y2[32];
  #pragma unroll
  for (int o=0;o<32;o++){
    float dot=0.f;
    #pragma unroll
    for (int c=0;c<32;c++) dot += sw[o*32+c]*y1[c];
    float v = dot*ka[o] + kb[o];
    y2[o] = (v>=0.f)?v:0.01f*v;
    lutf[t*32+o] = y2[o];
  }
  #pragma unroll
  for (int j=0;j<16;j++)
    lutb[t*16+j] = f2bf(y2[2*j]) | (f2bf(y2[2*j+1]) << 16);
}

// ---------------- K6: gather LUT -> output, pixel-pair packed stores ----------------
__global__ __launch_bounds__(256) void k_out(const u16* __restrict__ triple, const float* __restrict__ lutf,
                                             const u32* __restrict__ lutb,
                                             void* __restrict__ out, const u32* __restrict__ flag){
  u32 f = *flag;
  int g = blockIdx.x*256 + threadIdx.x;
  if (g >= NPIX/2) return;
  int p0 = g*2;
  int bimg = p0 / PP; int pix = p0 - bimg*PP;
  u32 tt = *(const u32*)(triple + p0);
  u32 ia = tt & 0xFFFFu, ib = tt >> 16;
  if (f){  // float32 output path
    const float4* La = (const float4*)(lutf + (size_t)ia*32);
    const float4* Lb = (const float4*)(lutf + (size_t)ib*32);
    float* ob = (float*)out + (size_t)bimg*32*PP + pix;
    #pragma unroll
    for (int j=0;j<8;j++){
      float4 a = La[j]; float4 b = Lb[j];
      float2 v;
      v.x=a.x; v.y=b.x; *(float2*)(ob + (size_t)(4*j+0)*PP) = v;
      v.x=a.y; v.y=b.y; *(float2*)(ob + (size_t)(4*j+1)*PP) = v;
      v.x=a.z; v.y=b.z; *(float2*)(ob + (size_t)(4*j+2)*PP) = v;
      v.x=a.w; v.y=b.w; *(float2*)(ob + (size_t)(4*j+3)*PP) = v;
    }
  } else { // bf16 output: packed-bf16 LUT rows (64 B = 1 line per pixel), v_perm interleave
    const uint4* La = (const uint4*)(lutb + (size_t)ia*16);
    const uint4* Lb = (const uint4*)(lutb + (size_t)ib*16);
    u16* ob = (u16*)out + (size_t)bimg*32*PP + pix;
    #pragma unroll
    for (int j=0;j<4;j++){
      uint4 A = La[j]; uint4 B = Lb[j];
      *(u32*)(ob + (size_t)(8*j+0)*PP) = __builtin_amdgcn_perm(B.x, A.x, 0x05040100u);
      *(u32*)(ob + (size_t)(8*j+1)*PP) = __builtin_amdgcn_perm(B.x, A.x, 0x07060302u);
      *(u32*)(ob + (size_t)(8*j+2)*PP) = __builtin_amdgcn_perm(B.y, A.y, 0x05040100u);
      *(u32*)(ob + (size_t)(8*j+3)*PP) = __builtin_amdgcn_perm(B.y, A.y, 0x07060302u);
      *(u32*)(ob + (size_t)(8*j+4)*PP) = __builtin_amdgcn_perm(B.z, A.z, 0x05040100u);
      *(u32*)(ob + (size_t)(8*j+5)*PP) = __builtin_amdgcn_perm(B.z, A.z, 0x07060302u);
      *(u32*)(ob + (size_t)(8*j+6)*PP) = __builtin_amdgcn_perm(B.w, A.w, 0x05040100u);
      *(u32*)(ob + (size_t)(8*j+7)*PP) = __builtin_amdgcn_perm(B.w, A.w, 0x07060302u);
    }
  }
}

extern "C" void kernel_launch(void* const* d_in, const int* in_sizes, int n_in,
                              void* d_out, int out_size, void* d_ws, size_t ws_size,
                              hipStream_t stream){
  const void* x   = d_in[0];
  const void* w1  = d_in[1];
  const void* b1  = d_in[2];
  const void* wd1 = d_in[3];
  const void* bd1 = d_in[4];
  const void* g1  = d_in[5];
  const void* be1 = d_in[6];
  const void* w2  = d_in[7];
  const void* b2  = d_in[8];
  const void* wd2 = d_in[9];
  const void* bd2 = d_in[10];
  const void* g2  = d_in[11];
  const void* be2 = d_in[12];

  char* w = (char*)d_ws;
  auto alloc = [&](size_t bytes)->char* { char* p = w; w += (bytes + 255) & ~(size_t)255; return p; };
  u32*   flag   = (u32*)  alloc(256);
  u8*    bins   = (u8*)   alloc(24ull*PADP);       // 6.34 MB
  u8*    modes  = (u8*)   alloc(24ull*PP);         // 6.10 MB
  u16*   triple = (u16*)  alloc(2ull*NPIX);        // 4.06 MB
  u32*   hist   = (u32*)  alloc(4ull*NTRIP);
  double* sums2 = (double*)alloc(64ull*8);
  float* lutf   = (float*)alloc(4ull*NTRIP*32);    // 629 KB
  u32*   lutb   = (u32*)  alloc(4ull*NTRIP*16);    // 314 KB

  k_init<<<dim3(1), 256, 0, stream>>>((const u16*)x, flag, hist);
  k_bins<<<dim3((PADP+255)/256, 24), 256, 0, stream>>>(x, bins, flag);
  k_mode<<<dim3(36, 24), 512, 0, stream>>>(bins, modes);
  k_triple<<<dim3(1984), 256, 0, stream>>>(modes, triple, hist);
  k_stats2<<<dim3(32), 256, 0, stream>>>(hist, w1,b1,wd1,bd1,g1,be1, w2,b2,wd2,bd2, sums2, flag);
  k_lut<<<dim3((NTRIP+255)/256), 256, 0, stream>>>(hist, sums2, w1,b1,wd1,bd1,g1,be1,
                                                   w2,b2,wd2,bd2, g2,be2, lutf, lutb, flag);
  k_out<<<dim3((NPIX/2)/256), 256, 0, stream>>>(triple, lutf, lutb, d_out, flag);
}

// Round 4
// 387.430 us; speedup vs baseline: 1.3144x; 1.1424x over previous
//
#include <hip/hip_runtime.h>
#include <hip/hip_bf16.h>

typedef unsigned char u8;
typedef unsigned short u16;
typedef unsigned int u32;
typedef unsigned long long u64;

#define PP     254016   // 504*504
#define NPIX   2032128  // 8*PP
#define NTRIP  4913     // 17^3
#define N_F    2032128.0
#define RROWS  4        // output rows per block strip; 504 = 4*126
#define NRB    126

__device__ __forceinline__ float bf2f(__hip_bfloat16 h){ return __bfloat162float(h); }
__device__ __forceinline__ u32 f2bf(float f){
  u32 u = __float_as_uint(f);
  return ((u + 0x7FFFu + ((u >> 16) & 1u)) >> 16);   // RNE
}
// dual-dtype load: flag==1 -> float32, flag==0 -> bf16
__device__ __forceinline__ float ldv(const void* p, int i, u32 f){
  return f ? ((const float*)p)[i] : bf2f(((const __hip_bfloat16*)p)[i]);
}

typedef unsigned short us2 __attribute__((ext_vector_type(2)));
__device__ __forceinline__ u32 pkmax(u32 a, u32 b){
  us2 x = __builtin_bit_cast(us2, a);
  us2 y = __builtin_bit_cast(us2, b);
  us2 r = __builtin_elementwise_max(x, y);
  return __builtin_bit_cast(u32, r);
}

// padded-coord bin: 0 on the 1-ring pad, else round(x*255/16) in [0,16]
__device__ __forceinline__ u32 getbin(const void* x, u32 f, int img, int ch, int pr, int pc){
  if ((u32)(pr-1) < 512u && (u32)(pc-1) < 512u){
    float xv = ldv(x, ((img*3+ch)*512 + (pr-1))*512 + (pc-1), f);
    return (u32)(int)rintf(xv * 255.0f * 0.0625f);
  }
  return 0u;
}
__device__ __forceinline__ u64 bdelta(u32 b){ return (b < 16u) ? (1ull << (b*4)) : 0ull; }

// ---------------- K0: dtype detect + hist zero (1 block) ----------------
__global__ __launch_bounds__(256) void k_init(const u16* __restrict__ xw, u32* __restrict__ flag,
                                              u32* __restrict__ hist){
  int t = threadIdx.x;
  for (int i=t; i<NTRIP; i+=256) hist[i] = 0u;
  if (t < 64){
    u32 bad = 0;
    for (int i=t; i<1024; i+=64) bad |= (u32)(xw[i] >> 15);
    int anybad = __any((int)bad);
    if (t == 0) *flag = anybad ? 1u : 0u;
  }
}

// ---------------- K1: fused bins + 11x11 mode + triple + histogram ----------------
// Block = (image, 4-row strip). All 3 channels. Vertical counts: nibble-packed u64
// per column in LDS (bins 0..15; bin16 = 121 - sum). Register nibble-ring remembers
// the last 11 bins per owned column so row-removal needs no global re-read.
__global__ __launch_bounds__(512) void k_fused(const void* __restrict__ x, const u32* __restrict__ flag,
                                               u16* __restrict__ triple, u32* __restrict__ hist){
  u32 f = *flag;
  int img = blockIdx.y;
  int r0 = blockIdx.x * RROWS;
  int t = threadIdx.x;
  __shared__ u64 CNT[3][518];
  __shared__ u32 lh[NTRIP];
  for (int i=t; i<NTRIP; i+=512) lh[i] = 0u;

  bool extra = (t < 2);
  int colB = 512 + t;
  u64 v[3] = {0,0,0}, vb[3] = {0,0,0};
  u64 rn[3] = {0,0,0}, rnb[3] = {0,0,0};
  u32 r16[3] = {0,0,0}, r16b[3] = {0,0,0};

  // prime: padded rows r0..r0+10
  for (int j=0; j<11; j++){
    int pr = r0 + j;
    #pragma unroll
    for (int ch=0; ch<3; ch++){
      u32 b = getbin(x, f, img, ch, pr, t);
      v[ch] += bdelta(b);
      rn[ch] = (rn[ch] << 4) | (u64)(b & 15u);
      r16[ch] = (r16[ch] << 1) | (b >> 4);
    }
    if (extra){
      #pragma unroll
      for (int ch=0; ch<3; ch++){
        u32 b = getbin(x, f, img, ch, pr, colB);
        vb[ch] += bdelta(b);
        rnb[ch] = (rnb[ch] << 4) | (u64)(b & 15u);
        r16b[ch] = (r16b[ch] << 1) | (b >> 4);
      }
    }
  }
  #pragma unroll
  for (int ch=0; ch<3; ch++) CNT[ch][t] = v[ch];
  if (extra){
    #pragma unroll
    for (int ch=0; ch<3; ch++) CNT[ch][colB] = vb[ch];
  }
  __syncthreads();

  for (int i=0; i<RROWS; i++){
    int r = r0 + i;
    if (t < 504){
      u32 m3[3];
      #pragma unroll
      for (int ch=0; ch<3; ch++){
        u64 he = 0, ho = 0;
        #pragma unroll
        for (int dx=0; dx<11; dx++){
          u64 n = CNT[ch][t+dx];
          he += n & 0x0F0F0F0F0F0F0F0Full;
          ho += (n >> 4) & 0x0F0F0F0F0F0F0F0Full;
        }
        u64 T = he + ho;                       // byte sums <= 242, no carry
        u32 T2 = (u32)T + (u32)(T >> 32);      // byte sums <= 242, no carry
        u32 s = (T2 & 0xFFu) + ((T2>>8)&0xFFu) + ((T2>>16)&0xFFu) + (T2>>24);
        u32 e_lo = (u32)he, e_hi = (u32)(he >> 32);
        u32 o_lo = (u32)ho, o_hi = (u32)(ho >> 32);
        u32 k0 = ((e_lo & 0x00FF00FFu) << 5) | 0x000C0010u;  // bins 0,4  -> idx 16,12
        u32 k1 = ((e_lo >> 3) & 0x1FE01FE0u) | 0x000A000Eu;  // bins 2,6  -> idx 14,10
        u32 k2 = ((e_hi & 0x00FF00FFu) << 5) | 0x00040008u;  // bins 8,12 -> idx 8,4
        u32 k3 = ((e_hi >> 3) & 0x1FE01FE0u) | 0x00020006u;  // bins 10,14-> idx 6,2
        u32 k4 = ((o_lo & 0x00FF00FFu) << 5) | 0x000B000Fu;  // bins 1,5  -> idx 15,11
        u32 k5 = ((o_lo >> 3) & 0x1FE01FE0u) | 0x0009000Du;  // bins 3,7  -> idx 13,9
        u32 k6 = ((o_hi & 0x00FF00FFu) << 5) | 0x00030007u;  // bins 9,13 -> idx 7,3
        u32 k7 = ((o_hi >> 3) & 0x1FE01FE0u) | 0x00010005u;  // bins 11,15-> idx 5,1
        u32 m = pkmax(pkmax(pkmax(k0,k1), pkmax(k2,k3)), pkmax(pkmax(k4,k5), pkmax(k6,k7)));
        u32 best = m >> 16, blo = m & 0xFFFFu;
        best = best > blo ? best : blo;
        u32 k16 = (121u - s) << 5;             // bin16: idx 0, loses all ties
        best = best > k16 ? best : k16;
        m3[ch] = 16u - (best & 31u);
      }
      u32 idx = (m3[0]*17u + m3[1])*17u + m3[2];
      triple[img*PP + r*504 + t] = (u16)idx;
      atomicAdd(&lh[idx], 1u);
    }
    __syncthreads();
    if (i+1 < RROWS){
      #pragma unroll
      for (int ch=0; ch<3; ch++){
        u32 nb = getbin(x, f, img, ch, r+11, t);
        rn[ch] = (rn[ch] << 4) | (u64)(nb & 15u);
        r16[ch] = (r16[ch] << 1) | (nb >> 4);
        u32 ob = (u32)((rn[ch] >> 44) & 15u);
        u32 o16 = (r16[ch] >> 11) & 1u;
        v[ch] += bdelta(nb);
        v[ch] -= o16 ? 0ull : (1ull << (ob*4));
        CNT[ch][t] = v[ch];
      }
      if (extra){
        #pragma unroll
        for (int ch=0; ch<3; ch++){
          u32 nb = getbin(x, f, img, ch, r+11, colB);
          rnb[ch] = (rnb[ch] << 4) | (u64)(nb & 15u);
          r16b[ch] = (r16b[ch] << 1) | (nb >> 4);
          u32 ob = (u32)((rnb[ch] >> 44) & 15u);
          u32 o16 = (r16b[ch] >> 11) & 1u;
          vb[ch] += bdelta(nb);
          vb[ch] -= o16 ? 0ull : (1ull << (ob*4));
          CNT[ch][colB] = vb[ch];
        }
      }
    }
    __syncthreads();
  }
  for (int i=t; i<NTRIP; i+=512){ u32 c = lh[i]; if (c) atomicAdd(&hist[i], c); }
}

// ---- shared device helper: 9 integer moments + stage-1 folded P1 (all 256 threads) ----
__device__ __forceinline__ void compute_P1(const u32* __restrict__ hist,
    const void* w1, const void* b1, const void* wd1, const void* bd1,
    const void* g1, const void* be1, u32 f, float* sP /*LDS[128]*/,
    u32* wred /*LDS[36]*/, u32* mom /*LDS[9]*/){
  u32 a0=0,a1=0,a2=0,a3=0,a4=0,a5=0,a6=0,a7=0,a8=0;
  for (int t=threadIdx.x; t<NTRIP; t+=256){
    u32 c = hist[t];
    int m2 = t % 17; int tt = t/17; int m1 = tt % 17; int m0 = tt/17;
    a0 += c*m0; a1 += c*m1; a2 += c*m2;
    a3 += c*m0*m0; a4 += c*m1*m1; a5 += c*m2*m2;
    a6 += c*m0*m1; a7 += c*m0*m2; a8 += c*m1*m2;
  }
  #pragma unroll
  for (int s=1; s<64; s<<=1){
    a0 += __shfl_xor(a0,s); a1 += __shfl_xor(a1,s); a2 += __shfl_xor(a2,s);
    a3 += __shfl_xor(a3,s); a4 += __shfl_xor(a4,s); a5 += __shfl_xor(a5,s);
    a6 += __shfl_xor(a6,s); a7 += __shfl_xor(a7,s); a8 += __shfl_xor(a8,s);
  }
  int wv = threadIdx.x >> 6;
  if ((threadIdx.x & 63) == 0){
    wred[wv*9+0]=a0; wred[wv*9+1]=a1; wred[wv*9+2]=a2; wred[wv*9+3]=a3; wred[wv*9+4]=a4;
    wred[wv*9+5]=a5; wred[wv*9+6]=a6; wred[wv*9+7]=a7; wred[wv*9+8]=a8;
  }
  __syncthreads();
  if (threadIdx.x < 9) mom[threadIdx.x] = wred[threadIdx.x] + wred[9+threadIdx.x] + wred[18+threadIdx.x] + wred[27+threadIdx.x];
  __syncthreads();
  if (threadIdx.x < 32){
    int o = threadIdx.x;
    double wd = ldv(wd1,o,f);
    double q0 = wd*ldv(w1,o*3+0,f), q1 = wd*ldv(w1,o*3+1,f), q2 = wd*ldv(w1,o*3+2,f);
    double qc = wd*ldv(b1,o,f) + ldv(bd1,o,f);
    double S0=mom[0],S1=mom[1],S2=mom[2],S00=mom[3],S11=mom[4],S22=mom[5],S01=mom[6],S02=mom[7],S12=mom[8];
    double lin = (q0*S0 + q1*S1 + q2*S2) * (1.0/16.0);
    double mean = lin/N_F + qc;
    double quad = (q0*q0*S00 + q1*q1*S11 + q2*q2*S22 + 2.0*(q0*q1*S01 + q0*q2*S02 + q1*q2*S12)) * (1.0/256.0);
    double Ev2 = quad/N_F + 2.0*qc*lin/N_F + qc*qc;
    double var = Ev2 - mean*mean;
    double rstd = 1.0 / sqrt(var + 1e-5);
    double A = rstd * ldv(g1,o,f);
    double B = ldv(be1,o,f) - mean*A;
    sP[o]      = (float)(q0*A);
    sP[32+o]   = (float)(q1*A);
    sP[64+o]   = (float)(q2*A);
    sP[96+o]   = (float)(qc*A + B);
  }
  __syncthreads();
}

// ---------------- K2: stage-2 BN sums (one block per output channel) ----------------
__global__ __launch_bounds__(256) void k_stats2(const u32* __restrict__ hist,
    const void* w1, const void* b1, const void* wd1, const void* bd1, const void* g1, const void* be1,
    const void* w2, const void* b2, const void* wd2, const void* bd2,
    double* __restrict__ sums2, const u32* __restrict__ flag){
  u32 f = *flag;
  int o = blockIdx.x;
  __shared__ float sP[128];
  __shared__ u32 wred[36], mom[9];
  __shared__ float sw[32];
  compute_P1(hist, w1,b1,wd1,bd1,g1,be1, f, sP, wred, mom);
  for (int i=threadIdx.x;i<32;i+=256) sw[i] = ldv(w2, o*32+i, f);
  __syncthreads();
  float wd = ldv(wd2, o, f);
  float cc = wd * ldv(b2, o, f) + ldv(bd2, o, f);
  double s=0.0, q=0.0;
  for (int t=threadIdx.x; t<NTRIP; t+=256){
    int m2 = t % 17; int tt = t / 17; int m1 = tt % 17; int m0 = tt / 17;
    float f0 = m0*(1.f/16.f), f1 = m1*(1.f/16.f), f2 = m2*(1.f/16.f);
    float dot = 0.f;
    #pragma unroll
    for (int c=0;c<32;c++){
      float u = sP[c]*f0 + sP[32+c]*f1 + sP[64+c]*f2 + sP[96+c];
      float y = (u >= 0.f) ? u : 0.01f*u;
      dot += sw[c]*y;
    }
    float v2 = wd*dot + cc;
    double cn = (double)hist[t];
    s += cn*(double)v2;
    q += cn*(double)v2*(double)v2;
  }
  __shared__ double red[256];
  red[threadIdx.x]=s; __syncthreads();
  for (int off=128; off>0; off>>=1){ if (threadIdx.x<off) red[threadIdx.x]+=red[threadIdx.x+off]; __syncthreads(); }
  if (threadIdx.x==0) sums2[o]=red[0];
  __syncthreads();
  red[threadIdx.x]=q; __syncthreads();
  for (int off=128; off>0; off>>=1){ if (threadIdx.x<off) red[threadIdx.x]+=red[threadIdx.x+off]; __syncthreads(); }
  if (threadIdx.x==0) sums2[32+o]=red[0];
}

// ---------------- K3: build LUTs (f32 and packed bf16) ----------------
__global__ __launch_bounds__(256) void k_lut(const u32* __restrict__ hist, const double* __restrict__ sums2,
    const void* w1, const void* b1, const void* wd1, const void* bd1, const void* g1, const void* be1,
    const void* w2, const void* b2, const void* wd2, const void* bd2,
    const void* g2, const void* be2,
    float* __restrict__ lutf, u32* __restrict__ lutb, const u32* __restrict__ flag){
  u32 f = *flag;
  __shared__ float sP[128];
  __shared__ u32 wred[36], mom[9];
  __shared__ float sw[1024];
  __shared__ float ka[32], kb[32];
  compute_P1(hist, w1,b1,wd1,bd1,g1,be1, f, sP, wred, mom);
  for (int i=threadIdx.x;i<1024;i+=256) sw[i]=ldv(w2, i, f);
  if (threadIdx.x < 32){
    int o = threadIdx.x;
    double mean = sums2[o] / N_F;
    double var  = sums2[32+o] / N_F - mean*mean;
    double rstd = 1.0 / sqrt(var + 1e-5);
    double A = rstd * (double)ldv(g2, o, f);
    double B = (double)ldv(be2, o, f) - mean*A;
    double wd = (double)ldv(wd2, o, f);
    ka[o] = (float)(wd*A);
    kb[o] = (float)((wd*(double)ldv(b2, o, f) + (double)ldv(bd2, o, f))*A + B);
  }
  __syncthreads();
  int t = blockIdx.x*256 + threadIdx.x;
  if (t >= NTRIP) return;
  int m2 = t % 17; int tt = t/17; int m1 = tt % 17; int m0 = tt/17;
  float f0=m0*(1.f/16.f), f1=m1*(1.f/16.f), f2=m2*(1.f/16.f);
  float y1[32];
  #pragma unroll
  for (int c=0;c<32;c++){
    float u = sP[c]*f0 + sP[32+c]*f1 + sP[64+c]*f2 + sP[96+c];
    y1[c] = (u>=0.f)?u:0.01f*u;
  }
  float y2[32];
  #pragma unroll
  for (int o=0;o<32;o++){
    float dot=0.f;
    #pragma unroll
    for (int c=0;c<32;c++) dot += sw[o*32+c]*y1[c];
    float v = dot*ka[o] + kb[o];
    y2[o] = (v>=0.f)?v:0.01f*v;
    lutf[t*32+o] = y2[o];
  }
  #pragma unroll
  for (int j=0;j<16;j++)
    lutb[t*16+j] = f2bf(y2[2*j]) | (f2bf(y2[2*j+1]) << 16);
}

// ---------------- K4: gather LUT -> output, pixel-pair packed stores ----------------
__global__ __launch_bounds__(256) void k_out(const u16* __restrict__ triple, const float* __restrict__ lutf,
                                             const u32* __restrict__ lutb,
                                             void* __restrict__ out, const u32* __restrict__ flag){
  u32 f = *flag;
  int g = blockIdx.x*256 + threadIdx.x;
  if (g >= NPIX/2) return;
  int p0 = g*2;
  int bimg = p0 / PP; int pix = p0 - bimg*PP;
  u32 tt = *(const u32*)(triple + p0);
  u32 ia = tt & 0xFFFFu, ib = tt >> 16;
  if (f){  // float32 output path
    const float4* La = (const float4*)(lutf + (size_t)ia*32);
    const float4* Lb = (const float4*)(lutf + (size_t)ib*32);
    float* ob = (float*)out + (size_t)bimg*32*PP + pix;
    #pragma unroll
    for (int j=0;j<8;j++){
      float4 a = La[j]; float4 b = Lb[j];
      float2 v;
      v.x=a.x; v.y=b.x; *(float2*)(ob + (size_t)(4*j+0)*PP) = v;
      v.x=a.y; v.y=b.y; *(float2*)(ob + (size_t)(4*j+1)*PP) = v;
      v.x=a.z; v.y=b.z; *(float2*)(ob + (size_t)(4*j+2)*PP) = v;
      v.x=a.w; v.y=b.w; *(float2*)(ob + (size_t)(4*j+3)*PP) = v;
    }
  } else { // bf16 output: packed-bf16 LUT rows (64 B/pixel), v_perm interleave
    const uint4* La = (const uint4*)(lutb + (size_t)ia*16);
    const uint4* Lb = (const uint4*)(lutb + (size_t)ib*16);
    u16* ob = (u16*)out + (size_t)bimg*32*PP + pix;
    #pragma unroll
    for (int j=0;j<4;j++){
      uint4 A = La[j]; uint4 B = Lb[j];
      *(u32*)(ob + (size_t)(8*j+0)*PP) = __builtin_amdgcn_perm(B.x, A.x, 0x05040100u);
      *(u32*)(ob + (size_t)(8*j+1)*PP) = __builtin_amdgcn_perm(B.x, A.x, 0x07060302u);
      *(u32*)(ob + (size_t)(8*j+2)*PP) = __builtin_amdgcn_perm(B.y, A.y, 0x05040100u);
      *(u32*)(ob + (size_t)(8*j+3)*PP) = __builtin_amdgcn_perm(B.y, A.y, 0x07060302u);
      *(u32*)(ob + (size_t)(8*j+4)*PP) = __builtin_amdgcn_perm(B.z, A.z, 0x05040100u);
      *(u32*)(ob + (size_t)(8*j+5)*PP) = __builtin_amdgcn_perm(B.z, A.z, 0x07060302u);
      *(u32*)(ob + (size_t)(8*j+6)*PP) = __builtin_amdgcn_perm(B.w, A.w, 0x05040100u);
      *(u32*)(ob + (size_t)(8*j+7)*PP) = __builtin_amdgcn_perm(B.w, A.w, 0x07060302u);
    }
  }
}

extern "C" void kernel_launch(void* const* d_in, const int* in_sizes, int n_in,
                              void* d_out, int out_size, void* d_ws, size_t ws_size,
                              hipStream_t stream){
  const void* x   = d_in[0];
  const void* w1  = d_in[1];
  const void* b1  = d_in[2];
  const void* wd1 = d_in[3];
  const void* bd1 = d_in[4];
  const void* g1  = d_in[5];
  const void* be1 = d_in[6];
  const void* w2  = d_in[7];
  const void* b2  = d_in[8];
  const void* wd2 = d_in[9];
  const void* bd2 = d_in[10];
  const void* g2  = d_in[11];
  const void* be2 = d_in[12];

  char* w = (char*)d_ws;
  auto alloc = [&](size_t bytes)->char* { char* p = w; w += (bytes + 255) & ~(size_t)255; return p; };
  u32*   flag   = (u32*)  alloc(256);
  u16*   triple = (u16*)  alloc(2ull*NPIX);        // 4.06 MB
  u32*   hist   = (u32*)  alloc(4ull*NTRIP);
  double* sums2 = (double*)alloc(64ull*8);
  float* lutf   = (float*)alloc(4ull*NTRIP*32);    // 629 KB
  u32*   lutb   = (u32*)  alloc(4ull*NTRIP*16);    // 314 KB

  k_init<<<dim3(1), 256, 0, stream>>>((const u16*)x, flag, hist);
  k_fused<<<dim3(NRB, 8), 512, 0, stream>>>(x, flag, triple, hist);
  k_stats2<<<dim3(32), 256, 0, stream>>>(hist, w1,b1,wd1,bd1,g1,be1, w2,b2,wd2,bd2, sums2, flag);
  k_lut<<<dim3((NTRIP+255)/256), 256, 0, stream>>>(hist, sums2, w1,b1,wd1,bd1,g1,be1,
                                                   w2,b2,wd2,bd2, g2,be2, lutf, lutb, flag);
  k_out<<<dim3((NPIX/2)/256), 256, 0, stream>>>(triple, lutf, lutb, d_out, flag);
}